// Round 3
// baseline (191.304 us; speedup 1.0000x reference)
//
#include <hip/hip_runtime.h>
#include <math.h>

#define IMG   512
#define TILE  64
#define HALO  9                  // 8 (gauss) + 1 (sobel)
#define AROWS 82                 // TILE + 2*HALO
#define ASTR  85                 // 85%32=21 -> row-strided access conflict-free
#define BROWS 66
#define BSTR  85
#define CSTR  68                 // sobel-input buffer stride (aliases sA)

__device__ __forceinline__ int reflect_idx(int i) {
    // numpy 'symmetric': -1 -> 0, -2 -> 1, ..., N -> N-1
    if (i < 0) i = -i - 1;
    if (i >= IMG) i = 2 * IMG - 1 - i;
    return i;
}

__global__ __launch_bounds__(256) void sobel_fused(
    const float* __restrict__ x, float* __restrict__ out)
{
    __shared__ float sA[AROWS * ASTR];   // 27880 B; phase3+ aliased as sC[66][CSTR]
    __shared__ float sB[BROWS * BSTR];   // 22440 B

    const int t  = threadIdx.x;
    const int w0 = blockIdx.x * TILE;
    const int h0 = blockIdx.y * TILE;
    const int b  = blockIdx.z;

    // 17-tap gaussian (sigma=2), f32 like numpy
    float gw[17];
    {
        float s = 0.f;
        #pragma unroll
        for (int i = 0; i < 17; ++i) {
            float xx = (float)(i - 8);
            gw[i] = expf(-0.125f * xx * xx);
            s += gw[i];
        }
        float inv = 1.0f / s;
        #pragma unroll
        for (int i = 0; i < 17; ++i) gw[i] *= inv;
    }

    // ---- phase 1: channel mean -> sA (reflect halo) ----
    const float* xb = x + (size_t)b * 3 * IMG * IMG;
    const float third = 1.0f / 3.0f;
    for (int idx = t; idx < AROWS * AROWS; idx += 256) {
        int r = idx / AROWS, c = idx - r * AROWS;
        int gr = reflect_idx(h0 - HALO + r);
        int gc = reflect_idx(w0 - HALO + c);
        const float* p = xb + gr * IMG + gc;
        sA[r * ASTR + c] = (p[0] + p[IMG * IMG] + p[2 * IMG * IMG]) * third;
    }
    __syncthreads();

    // ---- phase 2: H-blur, register sliding window ----
    // units: col c in [0,82) x row-seg in [0,3); each produces 22 blur rows
    if (t < 246) {
        int c   = t % 82;
        int seg = t / 82;
        int r0  = seg * 22;
        float acc[22];
        #pragma unroll
        for (int j = 0; j < 22; ++j) acc[j] = 0.f;
        #pragma unroll
        for (int i = 0; i < 38; ++i) {          // sA rows r0 .. r0+37
            float v = sA[(r0 + i) * ASTR + c];  // lane-consecutive c: conflict-free
            #pragma unroll
            for (int j = 0; j < 22; ++j) {
                int k = i - j;
                if (k >= 0 && k < 17) acc[j] += gw[k] * v;
            }
        }
        #pragma unroll
        for (int j = 0; j < 22; ++j) sB[(r0 + j) * BSTR + c] = acc[j];
    }
    __syncthreads();

    // ---- phase 3: W-blur, register sliding window; zero-ring; -> sC (=sA) ----
    float* sC = sA;   // sA dead after phase 2; 66*68 floats fit well inside
    if (t < 198) {
        int r   = t % 66;
        int seg = t / 66;
        int c0  = seg * 22;
        float acc[22];
        #pragma unroll
        for (int j = 0; j < 22; ++j) acc[j] = 0.f;
        #pragma unroll
        for (int i = 0; i < 38; ++i) {          // sB cols c0 .. c0+37 (max 81)
            float v = sB[r * BSTR + c0 + i];    // row stride 85: conflict-free
            #pragma unroll
            for (int j = 0; j < 22; ++j) {
                int k = i - j;
                if (k >= 0 && k < 17) acc[j] += gw[k] * v;
            }
        }
        int gr = h0 - 1 + r;
        #pragma unroll
        for (int j = 0; j < 22; ++j) {
            int c  = c0 + j;
            int gc = w0 - 1 + c;
            bool in = (gr >= 0) & (gr < IMG) & (gc >= 0) & (gc < IMG);
            sC[r * CSTR + c] = in ? acc[j] : 0.f;   // sobel zero-pad ring
        }
    }
    __syncthreads();

    // ---- phase 4: 3x3 sobel + hypot; 4 output rows per thread-iteration ----
    {
        int c  = t & 63;
        int rq = t >> 6;                       // 0..3
        #pragma unroll
        for (int it = 0; it < 4; ++it) {
            int r0 = (rq + it * 4) * 4;        // 0,4,...,60
            const float* bp = sC + r0 * CSTR + c;
            float m[6][3];
            #pragma unroll
            for (int rr = 0; rr < 6; ++rr) {
                #pragma unroll
                for (int cc = 0; cc < 3; ++cc)
                    m[rr][cc] = bp[rr * CSTR + cc];
            }
            #pragma unroll
            for (int dr = 0; dr < 4; ++dr) {
                float tl = m[dr][0],   tm = m[dr][1],   tr = m[dr][2];
                float ml = m[dr+1][0],                  mr = m[dr+1][2];
                float bl = m[dr+2][0], bm = m[dr+2][1], br2 = m[dr+2][2];
                float sx = (bl - tl) + 2.f * (bm - tm) + (br2 - tr);
                float sy = (tr - tl) + 2.f * (mr - ml) + (br2 - bl);
                out[((size_t)b * IMG + (h0 + r0 + dr)) * IMG + (w0 + c)]
                    = sqrtf(sx * sx + sy * sy);
            }
        }
    }
}

extern "C" void kernel_launch(void* const* d_in, const int* in_sizes, int n_in,
                              void* d_out, int out_size, void* d_ws, size_t ws_size,
                              hipStream_t stream) {
    const float* x = (const float*)d_in[0];
    float* out = (float*)d_out;
    dim3 grid(IMG / TILE, IMG / TILE, 32);   // 8 x 8 x 32 = 2048 blocks
    dim3 block(256);
    hipLaunchKernelGGL(sobel_fused, grid, block, 0, stream, x, out);
}

// Round 4
// 169.674 us; speedup vs baseline: 1.1275x; 1.1275x over previous
//
#include <hip/hip_runtime.h>
#include <math.h>

#define IMG   512
#define TILE  64
#define HALO  9                  // 8 (gauss) + 1 (sobel)
#define AROWS 82                 // TILE + 2*HALO
#define ASTR  82                 // phase-2 reads are lane-consecutive in c: any stride ok
#define BROWS 66
#define BSTR  83                 // 83%32=19, coprime -> phase-3 row-strided reads conflict-free
#define CSTR  67                 // 67%32=3,  coprime -> phase-3 column writes conflict-free

__device__ __forceinline__ int reflect_idx(int i) {
    // numpy 'symmetric': -1 -> 0, -2 -> 1, ..., N -> N-1
    if (i < 0) i = -i - 1;
    if (i >= IMG) i = 2 * IMG - 1 - i;
    return i;
}

__global__ __launch_bounds__(256) void sobel_fused(
    const float* __restrict__ x, float* __restrict__ out)
{
    __shared__ float sA[AROWS * ASTR];   // 26896 B; phase3+ aliased as sC[66][CSTR]
    __shared__ float sB[BROWS * BSTR];   // 21912 B

    const int t  = threadIdx.x;
    const int w0 = blockIdx.x * TILE;
    const int h0 = blockIdx.y * TILE;
    const int b  = blockIdx.z;

    // 17-tap gaussian (sigma=2), f32 like numpy
    float gw[17];
    {
        float s = 0.f;
        #pragma unroll
        for (int i = 0; i < 17; ++i) {
            float xx = (float)(i - 8);
            gw[i] = expf(-0.125f * xx * xx);
            s += gw[i];
        }
        float inv = 1.0f / s;
        #pragma unroll
        for (int i = 0; i < 17; ++i) gw[i] *= inv;
    }

    // ---- phase 1: channel mean -> sA (reflect halo) ----
    const float* xb = x + (size_t)b * 3 * IMG * IMG;
    const float third = 1.0f / 3.0f;
    for (int idx = t; idx < AROWS * AROWS; idx += 256) {
        int r = idx / AROWS, c = idx - r * AROWS;
        int gr = reflect_idx(h0 - HALO + r);
        int gc = reflect_idx(w0 - HALO + c);
        const float* p = xb + gr * IMG + gc;
        sA[r * ASTR + c] = (p[0] + p[IMG * IMG] + p[2 * IMG * IMG]) * third;
    }
    __syncthreads();

    // ---- phase 2: H-blur, register strip, ALL indices static ----
    // unit = (col c in [0,82)) x (row-seg in [0,3)); 22 outputs per unit
    if (t < 246) {
        int c   = t % 82;
        int seg = t / 82;
        int r0  = seg * 22;
        float v[38];
        #pragma unroll
        for (int i = 0; i < 38; ++i) v[i] = sA[(r0 + i) * ASTR + c];  // lane-consec c
        #pragma unroll
        for (int j = 0; j < 22; ++j) {
            float a = 0.f;
            #pragma unroll
            for (int k = 0; k < 17; ++k) a += gw[k] * v[j + k];
            sB[(r0 + j) * BSTR + c] = a;
        }
    }
    __syncthreads();

    // ---- phase 3: W-blur, register strip; zero-ring; -> sC (= sA) ----
    float* sC = sA;   // sA dead after phase 2; 66*67*4 = 17688 <= 26896
    if (t < 198) {
        int r   = t % 66;
        int seg = t / 66;
        int c0  = seg * 22;
        float v[38];
        #pragma unroll
        for (int i = 0; i < 38; ++i) v[i] = sB[r * BSTR + c0 + i];   // stride 83: CF
        int gr = h0 - 1 + r;
        bool rin = (gr >= 0) & (gr < IMG);
        #pragma unroll
        for (int j = 0; j < 22; ++j) {
            float a = 0.f;
            #pragma unroll
            for (int k = 0; k < 17; ++k) a += gw[k] * v[j + k];
            int gc = w0 - 1 + c0 + j;
            bool in = rin & (gc >= 0) & (gc < IMG);
            sC[r * CSTR + c0 + j] = in ? a : 0.f;   // stride 67: CF
        }
    }
    __syncthreads();

    // ---- phase 4: 3x3 sobel + hypot; 16 output rows per thread ----
    {
        int c  = t & 63;
        int rq = t >> 6;                       // 0..3
        #pragma unroll
        for (int it = 0; it < 4; ++it) {
            int r0 = (rq + it * 4) * 4;        // 0,4,...,60
            const float* bp = sC + r0 * CSTR + c;
            float m[6][3];
            #pragma unroll
            for (int rr = 0; rr < 6; ++rr) {
                #pragma unroll
                for (int cc = 0; cc < 3; ++cc)
                    m[rr][cc] = bp[rr * CSTR + cc];
            }
            #pragma unroll
            for (int dr = 0; dr < 4; ++dr) {
                float tl = m[dr][0],   tm = m[dr][1],   tr = m[dr][2];
                float ml = m[dr+1][0],                  mr = m[dr+1][2];
                float bl = m[dr+2][0], bm = m[dr+2][1], br2 = m[dr+2][2];
                float sx = (bl - tl) + 2.f * (bm - tm) + (br2 - tr);
                float sy = (tr - tl) + 2.f * (mr - ml) + (br2 - bl);
                out[((size_t)b * IMG + (h0 + r0 + dr)) * IMG + (w0 + c)]
                    = sqrtf(sx * sx + sy * sy);
            }
        }
    }
}

extern "C" void kernel_launch(void* const* d_in, const int* in_sizes, int n_in,
                              void* d_out, int out_size, void* d_ws, size_t ws_size,
                              hipStream_t stream) {
    const float* x = (const float*)d_in[0];
    float* out = (float*)d_out;
    dim3 grid(IMG / TILE, IMG / TILE, 32);   // 8 x 8 x 32 = 2048 blocks
    dim3 block(256);
    hipLaunchKernelGGL(sobel_fused, grid, block, 0, stream, x, out);
}

// Round 7
// 167.614 us; speedup vs baseline: 1.1413x; 1.0123x over previous
//
#include <hip/hip_runtime.h>
#include <math.h>

#define IMG   512
#define TILE  64
#define HALO  9                  // 8 (gauss) + 1 (sobel)
#define BROWS 66
#define BSTR  83                 // 83%32=19 coprime -> row-strided reads conflict-free
#define CSTR  67                 // 67%32=3  coprime -> column writes conflict-free

__device__ __forceinline__ int reflect_idx(int i) {
    // numpy 'symmetric': -1 -> 0, -2 -> 1, ..., N -> N-1
    if (i < 0) i = -i - 1;
    if (i >= IMG) i = 2 * IMG - 1 - i;
    return i;
}

__global__ __launch_bounds__(256) void sobel_fused(
    const float* __restrict__ x, float* __restrict__ out)
{
    __shared__ float sB[BROWS * BSTR];   // 21912 B : H-blurred rows [66][82 used]
    __shared__ float sC[BROWS * CSTR];   // 17688 B : fully blurred + zero ring

    const int t  = threadIdx.x;
    const int w0 = blockIdx.x * TILE;
    const int h0 = blockIdx.y * TILE;
    const int b  = blockIdx.z;

    // 17-tap gaussian (sigma=2): unnormalized exp constants (<=1ulp vs f32 expf),
    // normalization constant-folds at compile time (all operands constant).
    const float ge[9] = {1.0f, 0.882496903f, 0.606530660f, 0.324652467f,
                         0.135335283f, 0.0439369336f, 0.0111089965f,
                         0.00218749112f, 0.000335462628f};
    float gw[17];
    {
        float s = 0.f;
        #pragma unroll
        for (int i = 0; i < 17; ++i) { gw[i] = ge[(i < 8) ? (8 - i) : (i - 8)]; s += gw[i]; }
        float inv = 1.0f / s;
        #pragma unroll
        for (int i = 0; i < 17; ++i) gw[i] *= inv;
    }

    const float* xb = x + (size_t)b * 3 * IMG * IMG;
    const float third = 1.0f / 3.0f;

    // ---- phase A: global->reg channel-mean + H-blur (fused, no staging) ----
    // unit = (col c in [0,82)) x (row-seg in [0,3)); 22 blur rows per unit
    if (t < 246) {
        int c   = t % 82;
        int seg = t / 82;
        int r0  = seg * 22;
        int gc  = reflect_idx(w0 - HALO + c);           // lane-consecutive: coalesced
        const float* p0 = xb + gc;
        float v[38];
        #pragma unroll
        for (int i = 0; i < 38; ++i) {
            int gr = reflect_idx(h0 - HALO + r0 + i);
            const float* p = p0 + (size_t)gr * IMG;
            v[i] = (p[0] + p[IMG * IMG] + p[2 * IMG * IMG]) * third;
        }
        #pragma unroll
        for (int j = 0; j < 22; ++j) {
            float a = 0.f;
            #pragma unroll
            for (int k = 0; k < 17; ++k) a += gw[k] * v[j + k];
            sB[(r0 + j) * BSTR + c] = a;                // lane-consec c: CF
        }
    }
    __syncthreads();

    // ---- phase B: W-blur, register strip; zero-ring; -> sC ----
    if (t < 198) {
        int r   = t % 66;
        int seg = t / 66;
        int c0  = seg * 22;
        float v[38];
        #pragma unroll
        for (int i = 0; i < 38; ++i) v[i] = sB[r * BSTR + c0 + i];   // stride 83: CF
        int gr = h0 - 1 + r;
        bool rin = (gr >= 0) & (gr < IMG);
        #pragma unroll
        for (int j = 0; j < 22; ++j) {
            float a = 0.f;
            #pragma unroll
            for (int k = 0; k < 17; ++k) a += gw[k] * v[j + k];
            int gc = w0 - 1 + c0 + j;
            bool in = rin & (gc >= 0) & (gc < IMG);
            sC[r * CSTR + c0 + j] = in ? a : 0.f;       // stride 67: CF
        }
    }
    __syncthreads();

    // ---- phase C: 3x3 sobel + hypot; 16 output rows per thread ----
    {
        int c  = t & 63;
        int rq = t >> 6;                       // 0..3
        #pragma unroll
        for (int it = 0; it < 4; ++it) {
            int r0 = (rq + it * 4) * 4;        // 0,4,...,60
            const float* bp = sC + r0 * CSTR + c;
            float m[6][3];
            #pragma unroll
            for (int rr = 0; rr < 6; ++rr) {
                #pragma unroll
                for (int cc = 0; cc < 3; ++cc)
                    m[rr][cc] = bp[rr * CSTR + cc];
            }
            #pragma unroll
            for (int dr = 0; dr < 4; ++dr) {
                float tl = m[dr][0],   tm = m[dr][1],   tr = m[dr][2];
                float ml = m[dr+1][0],                  mr = m[dr+1][2];
                float bl = m[dr+2][0], bm = m[dr+2][1], br2 = m[dr+2][2];
                float sx = (bl - tl) + 2.f * (bm - tm) + (br2 - tr);
                float sy = (tr - tl) + 2.f * (mr - ml) + (br2 - bl);
                out[((size_t)b * IMG + (h0 + r0 + dr)) * IMG + (w0 + c)]
                    = sqrtf(sx * sx + sy * sy);
            }
        }
    }
}

extern "C" void kernel_launch(void* const* d_in, const int* in_sizes, int n_in,
                              void* d_out, int out_size, void* d_ws, size_t ws_size,
                              hipStream_t stream) {
    const float* x = (const float*)d_in[0];
    float* out = (float*)d_out;
    dim3 grid(IMG / TILE, IMG / TILE, 32);   // 8 x 8 x 32 = 2048 blocks
    dim3 block(256);
    hipLaunchKernelGGL(sobel_fused, grid, block, 0, stream, x, out);
}